// Round 13
// baseline (609.299 us; speedup 1.0000x reference)
//
#include <hip/hip_runtime.h>
#include <hip/hip_bf16.h>
#include <hip/hip_fp8.h>

// Problem constants
#define TB 2
#define TS 2048
#define TD 1024
#define TH 16
#define THD 64
#define TE 8
#define TKK 2
#define TF 4096
#define TT (TB*TS)      // 4096 tokens
#define QLD (3*TD)      // 3072
#define NSLOT (TT*TKK)  // 8192
#define MAXT128 72      // max live 128-row tiles over all experts

typedef unsigned short u16;
typedef unsigned char u8;
typedef __attribute__((ext_vector_type(8))) __bf16 bf16x8;
typedef __attribute__((ext_vector_type(8))) u16 u16x8;
typedef __attribute__((ext_vector_type(4))) u16 u16x4;
typedef __attribute__((ext_vector_type(4))) u8 u8x4;
typedef __attribute__((ext_vector_type(4))) float f32x4;

static __device__ __forceinline__ u16 f2bf(float f){
  __hip_bfloat16 h = __float2bfloat16(f);
  return __builtin_bit_cast(u16, h);
}
static __device__ __forceinline__ float bf2f(u16 b){
  return __builtin_bit_cast(float, (unsigned)b << 16);
}
static __device__ __forceinline__ u8 f2e4m3(float f){
  __hip_fp8_e4m3 q(f);           // OCP e4m3fn on gfx950
  return q.__x;
}

#define MFMA16(a,b,c) __builtin_amdgcn_mfma_f32_16x16x32_bf16((a),(b),(c),0,0,0)
#define MFMA8(a,b,c)  __builtin_amdgcn_mfma_f32_16x16x32_fp8_fp8((a),(b),(c),0,0,0)
#define GLL16(g, l) __builtin_amdgcn_global_load_lds( \
    (const __attribute__((address_space(1))) unsigned int*)(g), \
    (__attribute__((address_space(3))) unsigned int*)(l), 16, 0, 0)

// ---------------------------------------------------------------- utilities
__global__ __launch_bounds__(256)
void cast_bf_kernel(const float* __restrict__ in, u16* __restrict__ out, int n4){
  int i = blockIdx.x*256 + threadIdx.x;
  if (i < n4){
    float4 v = ((const float4*)in)[i];
    u16x4 o = { f2bf(v.x), f2bf(v.y), f2bf(v.z), f2bf(v.w) };
    ((u16x4*)out)[i] = o;
  }
}

__global__ __launch_bounds__(256)
void cast_f8_kernel(const float* __restrict__ in, u8* __restrict__ out, int n4){
  int i = blockIdx.x*256 + threadIdx.x;
  if (i < n4){
    float4 v = ((const float4*)in)[i];
    u8x4 o = { f2e4m3(v.x), f2e4m3(v.y), f2e4m3(v.z), f2e4m3(v.w) };
    ((u8x4*)out)[i] = o;
  }
}

// out[z][c][r] = (fp8) in[z][r][c]   (R,C multiples of 32)
__global__ __launch_bounds__(256)
void transpose_cast_f8_kernel(const float* __restrict__ in, u8* __restrict__ out,
                              int R, int C){
  __shared__ float tile[32][33];
  const size_t mo = (size_t)blockIdx.z * R * C;
  const float* ip = in + mo;
  u8* op = out + mo;
  const int c0 = blockIdx.x*32, r0 = blockIdx.y*32;
  const int lx = threadIdx.x & 31, ly = threadIdx.x >> 5;   // 32 x 8
#pragma unroll
  for (int i2 = 0; i2 < 4; ++i2)
    tile[ly + i2*8][lx] = ip[(size_t)(r0 + ly + i2*8)*C + c0 + lx];
  __syncthreads();
#pragma unroll
  for (int i2 = 0; i2 < 4; ++i2)
    op[(size_t)(c0 + ly + i2*8)*R + r0 + lx] = f2e4m3(tile[lx][ly + i2*8]);
}

__global__ void zero_counts_kernel(int* counts){
  if (threadIdx.x < TE) counts[threadIdx.x] = 0;
}

// ---------------------------------------- layernorm 1 (fp8 out for QKV GEMM)
__global__ __launch_bounds__(256)
void ln1_kernel(const float* __restrict__ x, const float* __restrict__ g,
                const float* __restrict__ bb, u8* __restrict__ h8){
  const int t = blockIdx.x, tid = threadIdx.x;
  const float4 v = ((const float4*)(x + (size_t)t*TD))[tid];
  float s  = v.x + v.y + v.z + v.w;
  float ss = v.x*v.x + v.y*v.y + v.z*v.z + v.w*v.w;
#pragma unroll
  for (int d = 32; d >= 1; d >>= 1){ s += __shfl_down(s, d); ss += __shfl_down(ss, d); }
  __shared__ float red[8];
  const int lane = tid & 63, wave = tid >> 6;
  if (lane == 0){ red[wave] = s; red[4+wave] = ss; }
  __syncthreads();
  const float S  = red[0]+red[1]+red[2]+red[3];
  const float SS = red[4]+red[5]+red[6]+red[7];
  const float mu = S * (1.f/TD);
  const float rstd = rsqrtf(SS*(1.f/TD) - mu*mu + 1e-5f);
  const float4 gv = ((const float4*)g)[tid];
  const float4 bv = ((const float4*)bb)[tid];
  u8x4 o = { f2e4m3((v.x-mu)*rstd*gv.x + bv.x),
             f2e4m3((v.y-mu)*rstd*gv.y + bv.y),
             f2e4m3((v.z-mu)*rstd*gv.z + bv.z),
             f2e4m3((v.w-mu)*rstd*gv.w + bv.w) };
  ((u8x4*)(h8 + (size_t)t*TD))[tid] = o;
}

// --------------------- layernorm 2 + fp32 router (h2 emitted as fp8 for MoE)
__global__ __launch_bounds__(256)
void ln2_router_kernel(const float* __restrict__ xo, const float* __restrict__ g,
                       const float* __restrict__ bb, u8* __restrict__ h2f8,
                       const float* __restrict__ rw, const float* __restrict__ rb,
                       int* __restrict__ counts, int* __restrict__ topidx,
                       float* __restrict__ topw){
  const int t = blockIdx.x, tid = threadIdx.x;
  const float4 v = ((const float4*)(xo + (size_t)t*TD))[tid];
  float s  = v.x + v.y + v.z + v.w;
  float ss = v.x*v.x + v.y*v.y + v.z*v.z + v.w*v.w;
#pragma unroll
  for (int d = 32; d >= 1; d >>= 1){ s += __shfl_down(s, d); ss += __shfl_down(ss, d); }
  __shared__ float red[8];
  const int lane = tid & 63, wave = tid >> 6;
  if (lane == 0){ red[wave] = s; red[4+wave] = ss; }
  __syncthreads();
  const float S  = red[0]+red[1]+red[2]+red[3];
  const float SS = red[4]+red[5]+red[6]+red[7];
  const float mu = S * (1.f/TD);
  const float rstd = rsqrtf(SS*(1.f/TD) - mu*mu + 1e-5f);
  const float4 gv = ((const float4*)g)[tid];
  const float4 bv = ((const float4*)bb)[tid];
  float hv[4] = { (v.x-mu)*rstd*gv.x + bv.x, (v.y-mu)*rstd*gv.y + bv.y,
                  (v.z-mu)*rstd*gv.z + bv.z, (v.w-mu)*rstd*gv.w + bv.w };
  u8x4 o8 = { f2e4m3(hv[0]), f2e4m3(hv[1]), f2e4m3(hv[2]), f2e4m3(hv[3]) };
  ((u8x4*)(h2f8 + (size_t)t*TD))[tid] = o8;

  float acc[TE] = {0,0,0,0,0,0,0,0};
#pragma unroll
  for (int q = 0; q < 4; ++q){
    const int d = tid*4 + q;
    const float4 r0 = ((const float4*)(rw + (size_t)d*TE))[0];
    const float4 r1 = ((const float4*)(rw + (size_t)d*TE))[1];
    acc[0] += hv[q]*r0.x; acc[1] += hv[q]*r0.y; acc[2] += hv[q]*r0.z; acc[3] += hv[q]*r0.w;
    acc[4] += hv[q]*r1.x; acc[5] += hv[q]*r1.y; acc[6] += hv[q]*r1.z; acc[7] += hv[q]*r1.w;
  }
#pragma unroll
  for (int d = 32; d >= 1; d >>= 1)
#pragma unroll
    for (int e = 0; e < TE; ++e) acc[e] += __shfl_down(acc[e], d);
  __shared__ float racc[4][TE];
  if (lane == 0)
#pragma unroll
    for (int e = 0; e < TE; ++e) racc[wave][e] = acc[e];
  __syncthreads();
  if (tid == 0){
    float lg[TE];
#pragma unroll
    for (int e = 0; e < TE; ++e)
      lg[e] = racc[0][e] + racc[1][e] + racc[2][e] + racc[3][e] + rb[e];
    int e1 = 0;
    for (int e = 1; e < TE; ++e) if (lg[e] > lg[e1]) e1 = e;
    int e2 = -1;
    for (int e = 0; e < TE; ++e){ if (e == e1) continue; if (e2 < 0 || lg[e] > lg[e2]) e2 = e; }
    const float w1 = 1.f / (1.f + __expf(lg[e2] - lg[e1]));
    const float w2 = 1.f / (1.f + __expf(lg[e1] - lg[e2]));
    topidx[t*2]   = e1;  topidx[t*2+1] = e2;
    topw[t*2]     = w1;  topw[t*2+1]   = w2;
    atomicAdd(&counts[e1], 1);
    atomicAdd(&counts[e2], 1);
  }
}

// offsets + compact 128-row tile map (tilemap[i] = (e<<16)|mt ; tilemap[95] = nt)
__global__ void offsets_kernel(const int* __restrict__ counts, int* __restrict__ offs,
                               int* __restrict__ cursors, float* __restrict__ load_out,
                               int* __restrict__ tilemap){
  if (threadIdx.x == 0){
    int off = 0, nt = 0;
    for (int e = 0; e < TE; ++e){
      offs[e] = off; cursors[e] = off;
      load_out[e] = (float)counts[e];
      for (int mt = 0; mt*128 < counts[e]; ++mt) tilemap[nt++] = (e << 16) | mt;
      off += counts[e];
    }
    tilemap[95] = nt;
  }
}

__global__ __launch_bounds__(256)
void scatter_kernel(const int* __restrict__ topidx, const float* __restrict__ topw,
                    int* __restrict__ cursors, int* __restrict__ assign_tok,
                    float* __restrict__ assign_w, int* __restrict__ token_slot){
  const int t = blockIdx.x*256 + threadIdx.x;
  if (t >= TT) return;
#pragma unroll
  for (int k = 0; k < 2; ++k){
    const int e = topidx[t*2 + k];
    const int pos = atomicAdd(&cursors[e], 1);
    assign_tok[pos] = t;
    assign_w[pos]   = topw[t*2 + k];
    token_slot[t*2 + k] = pos;
  }
}

// ------------------- 128x128 bf16 GEMM (m97 structure) — O-proj only
__global__ __launch_bounds__(256)
void gemm_bt(const u16* __restrict__ A, const u16* __restrict__ Bt,
             const float* __restrict__ bias, const float* __restrict__ resid,
             float* __restrict__ outF, const int K)
{
  __shared__ u16 As[2][128*32];
  __shared__ u16 Bs[2][128*32];
  const int tid = threadIdx.x;
  const int n0  = blockIdx.x * 128;
  const int row0 = blockIdx.y * 128;
  const int srow = tid >> 2, skseg = tid & 3;
  const u16* aptr[2];
  const u16* bptr[2];
#pragma unroll
  for (int it = 0; it < 2; ++it){
    const int r = it*64 + srow;
    aptr[it] = A + (size_t)(row0 + r)*K + skseg*8;
    bptr[it] = Bt + (size_t)(n0 + it*64 + srow)*K + skseg*8;
  }

#define STAGE(buf, kt) do {                                        \
    _Pragma("unroll")                                              \
    for (int it = 0; it < 2; ++it){                                \
      GLL16(aptr[it] + (size_t)(kt)*32, &As[buf][it*2048 + tid*8]);\
      GLL16(bptr[it] + (size_t)(kt)*32, &Bs[buf][it*2048 + tid*8]);\
    } } while(0)

  const int lane = tid & 63, wave = tid >> 6;
  const int wm = (wave >> 1) * 64, wn = (wave & 1) * 64;
  const int r16 = lane & 15, kgr = lane >> 4;
  const f32x4 z4 = {0.f,0.f,0.f,0.f};
  f32x4 acc[4][4];
#pragma unroll
  for (int i = 0; i < 4; ++i)
#pragma unroll
    for (int j = 0; j < 4; ++j) acc[i][j] = z4;

  STAGE(0, 0);
  __syncthreads();
  const int nk = K >> 5;
  for (int kt = 0; kt < nk; ++kt){
    const int cur = kt & 1;
    if (kt + 1 < nk) STAGE(cur ^ 1, kt + 1);
    bf16x8 a[4], b[4];
#pragma unroll
    for (int i = 0; i < 4; ++i)
      a[i] = *(const bf16x8*)&As[cur][(wm + i*16 + r16)*32 + kgr*8];
#pragma unroll
    for (int j = 0; j < 4; ++j)
      b[j] = *(const bf16x8*)&Bs[cur][(wn + j*16 + r16)*32 + kgr*8];
#pragma unroll
    for (int i = 0; i < 4; ++i)
#pragma unroll
      for (int j = 0; j < 4; ++j)
        acc[i][j] = MFMA16(a[i], b[j], acc[i][j]);
    __syncthreads();
  }
#undef STAGE

#pragma unroll
  for (int i = 0; i < 4; ++i){
#pragma unroll
    for (int r = 0; r < 4; ++r){
      const int row = wm + i*16 + kgr*4 + r;
#pragma unroll
      for (int j = 0; j < 4; ++j){
        const int col = n0 + wn + j*16 + r16;
        const size_t idx = (size_t)(row0 + row)*TD + col;
        outF[idx] = acc[i][j][r] + bias[col] + resid[idx];
      }
    }
  }
}

// ------------------- 128x128 fp8 GEMM — QKV + MoE experts. BK=64, seg-major
// LDS layout [seg(4)][row(128)][16B]: staging tid -> (seg=tid>>7, row=tid&127),
// dest linear tid*16 (gload_lds constraint); 4 segs per operand per k-step.
// Fragment read (row,kk,kgr): addr = (kk*2+(kgr>>1))*2048 + row*16 + (kgr&1)*8
// -> 16-lane groups stride 4 dwords = banks {0,4..28}x2 + paired kgr fills odd
// slots = 2 accesses/bank = wave64 floor (m136: free). Row-major 32B layouts
// are inherently 4-way (row starts repeat mod 4 rows) — layout fix, not XOR.
// MODE 0: QKV  outBf = acc + bias (dense rows, QLD stride)
// MODE 2: MOE1 out8  = fp8(gelu(acc + b1[e]))  (A rows via assign_tok)
// MODE 3: MOE2 outBf = bf16((acc + b2[e]) * w[slot]) (TD stride)
template<int MODE>
__global__ __launch_bounds__(256)
void gemm_f8(const u8* __restrict__ A, const u8* __restrict__ Bt,
             const float* __restrict__ bias,
             u8* __restrict__ out8, u16* __restrict__ outBf,
             const int K, const int N,
             const int* __restrict__ counts, const int* __restrict__ offs,
             const int* __restrict__ assign_tok, const float* __restrict__ assign_w,
             const int* __restrict__ tilemap)
{
  __shared__ u8 As[2][128*64];   // [buf][seg*2048 + row*16]
  __shared__ u8 Bs[2][128*64];
  const int tid = threadIdx.x;
  const int n0 = blockIdx.x * 128;
  int row0 = 0, slotbase = 0, cntRem = 128, slotEnd = 0;
  if (MODE == 0){
    row0 = blockIdx.y * 128;
  } else {
    const int nt = tilemap[95];
    if ((int)blockIdx.y >= nt) return;
    const int ent = tilemap[blockIdx.y];
    const int e = ent >> 16, mt = ent & 0xffff;
    const int cnt = counts[e];
    slotbase = offs[e] + mt*128;
    slotEnd  = offs[e] + cnt;
    cntRem   = cnt - mt*128; if (cntRem > 128) cntRem = 128;
    Bt   += (size_t)e*K*N;
    bias += (size_t)e*N;
  }

  // staging coords: row = tid&127, seg = tid>>7 (k-chunk 0/1; +32B covers 2/3)
  const int srow = tid & 127, sseg = tid >> 7;
  const u8* aptr;
  const u8* bptr;
  if (MODE == 0){
    aptr = A + (size_t)(row0 + srow)*K + sseg*16;
  } else {
    int s2 = slotbase + srow; if (s2 > slotEnd-1) s2 = slotEnd-1;
    if (MODE == 2) aptr = A + (size_t)assign_tok[s2]*K + sseg*16;
    else           aptr = A + (size_t)s2*K + sseg*16;
  }
  bptr = Bt + (size_t)(n0 + srow)*K + sseg*16;
#define STAGE8(buf, kt) do{ \
    GLL16(aptr + (size_t)(kt)*64,      &As[buf][tid*16]); \
    GLL16(aptr + (size_t)(kt)*64 + 32, &As[buf][4096 + tid*16]); \
    GLL16(bptr + (size_t)(kt)*64,      &Bs[buf][tid*16]); \
    GLL16(bptr + (size_t)(kt)*64 + 32, &Bs[buf][4096 + tid*16]); }while(0)

  const int lane = tid & 63, wave = tid >> 6;
  const int wm = (wave >> 1) * 64, wn = (wave & 1) * 64;
  const int r16 = lane & 15, kgr = lane >> 4;
  int offA[4][2], offB[4][2];
#pragma unroll
  for (int f = 0; f < 4; ++f)
#pragma unroll
    for (int kk = 0; kk < 2; ++kk){
      const int seg = kk*2 + (kgr >> 1);
      offA[f][kk] = seg*2048 + (wm + f*16 + r16)*16 + (kgr & 1)*8;
      offB[f][kk] = seg*2048 + (wn + f*16 + r16)*16 + (kgr & 1)*8;
    }
  const f32x4 z4 = {0.f,0.f,0.f,0.f};
  f32x4 acc[4][4];
#pragma unroll
  for (int i = 0; i < 4; ++i)
#pragma unroll
    for (int j = 0; j < 4; ++j) acc[i][j] = z4;

  STAGE8(0, 0);
  __syncthreads();
  const int nk = K >> 6;          // 64 fp8 elements per K-step
  for (int kt = 0; kt < nk; ++kt){
    const int cur = kt & 1;
    if (kt + 1 < nk) STAGE8(cur ^ 1, kt + 1);
    long a[4][2], b[4][2];
#pragma unroll
    for (int f = 0; f < 4; ++f)
#pragma unroll
      for (int kk = 0; kk < 2; ++kk){
        a[f][kk] = *(const long*)&As[cur][offA[f][kk]];
        b[f][kk] = *(const long*)&Bs[cur][offB[f][kk]];
      }
#pragma unroll
    for (int kk = 0; kk < 2; ++kk)
#pragma unroll
      for (int i = 0; i < 4; ++i)
#pragma unroll
        for (int j = 0; j < 4; ++j)
          acc[i][j] = MFMA8(a[i][kk], b[j][kk], acc[i][j]);
    __syncthreads();
  }
#undef STAGE8

#pragma unroll
  for (int i = 0; i < 4; ++i){
#pragma unroll
    for (int r = 0; r < 4; ++r){
      const int row = wm + i*16 + kgr*4 + r;
      if (MODE != 0 && row >= cntRem) continue;
#pragma unroll
      for (int j = 0; j < 4; ++j){
        const int col = n0 + wn + j*16 + r16;
        float v = acc[i][j][r] + bias[col];
        if (MODE == 0){
          outBf[(size_t)(row0 + row)*QLD + col] = f2bf(v);
        } else if (MODE == 2){
          // gelu_tanh(v) == v * sigmoid(2*0.7978845608*(v + 0.044715 v^3))
          const float z = 1.5957691216057308f*(v + 0.044715f*v*v*v);
          const float g = v * __builtin_amdgcn_rcpf(1.f + __expf(-z));
          out8[(size_t)(slotbase + row)*TF + col] = f2e4m3(g);
        } else {
          outBf[(size_t)(slotbase + row)*TD + col] =
              f2bf(v * assign_w[slotbase + row]);
        }
      }
    }
  }
}

// ------------------------------------------------------- flash attention
__global__ __launch_bounds__(256)
void attn_kernel(const u16* __restrict__ qkv, u16* __restrict__ ctx){
  const int blk = blockIdx.x;
  const int pq = blk & 15, bh = blk >> 4;
  const int b = bh >> 4, h = bh & 15;
  const int tid = threadIdx.x, lane = tid & 63, wave = tid >> 6;
  const int r16 = lane & 15, kgr = lane >> 4;
  const size_t base = (size_t)b * TS * QLD;
  const u16* Q  = qkv + base + h*THD;
  const u16* Kp = qkv + base + TD + h*THD;
  const u16* Vp = qkv + base + 2*TD + h*THD;

  __shared__ u16 VT[2][64*64];     // V^T [hd][kv], XOR-swizzled
  __shared__ u16 Plds[4][16*64];   // per-wave P [q][kv], XOR-swizzled

  const int kvr0 = tid >> 3,          hs0 = tid & 7;
  const int kvr1 = (tid + 256) >> 3,  hs1 = tid & 7;
  const f32x4 z4 = {0.f,0.f,0.f,0.f};

  for (int qsel = 0; qsel < 2; ++qsel){
    const int qt = qsel ? (31 - pq) : pq;
    const int qw = qt*64 + wave*16;

    const bf16x8 qa0 = *(const bf16x8*)&Q[(size_t)(qw + r16)*QLD + kgr*8];
    const bf16x8 qa1 = *(const bf16x8*)&Q[(size_t)(qw + r16)*QLD + 32 + kgr*8];

    f32x4 O[4] = { z4, z4, z4, z4 };
    float m_r = -1e30f;
    float l_r = 0.f;

    u16x8 v0 = *(const u16x8*)&Vp[(size_t)kvr0*QLD + hs0*8];
    u16x8 v1 = *(const u16x8*)&Vp[(size_t)kvr1*QLD + hs1*8];

    __syncthreads();

    for (int kt = 0; kt <= qt; ++kt){
      const int kv0 = kt*64;
      u16* vt = &VT[kt & 1][0];
#pragma unroll
      for (int jj = 0; jj < 8; ++jj)
        vt[((hs0*8 + jj)*64 + kvr0) ^ (hs0<<3)] = v0[jj];
#pragma unroll
      for (int jj = 0; jj < 8; ++jj)
        vt[((hs1*8 + jj)*64 + kvr1) ^ (hs1<<3)] = v1[jj];
      if (kt < qt){
        v0 = *(const u16x8*)&Vp[(size_t)(kv0 + 64 + kvr0)*QLD + hs0*8];
        v1 = *(const u16x8*)&Vp[(size_t)(kv0 + 64 + kvr1)*QLD + hs1*8];
      }
      f32x4 s[4];
      __builtin_amdgcn_s_setprio(1);
#pragma unroll
      for (int j = 0; j < 4; ++j){
        const bf16x8 k0 = *(const bf16x8*)&Kp[(size_t)(kv0 + j*16 + r16)*QLD + kgr*8];
        const bf16x8 k1 = *(const bf16x8*)&Kp[(size_t)(kv0 + j*16 + r16)*QLD + 32 + kgr*8];
        s[j] = MFMA16(k0, qa0, z4);
        s[j] = MFMA16(k1, qa1, s[j]);
      }
      __builtin_amdgcn_s_setprio(0);
      const bool diag = (kt == qt);
      float mx = -3e38f;
#pragma unroll
      for (int j = 0; j < 4; ++j)
#pragma unroll
        for (int r = 0; r < 4; ++r){
          float v = s[j][r] * 0.125f;
          if (diag && (kv0 + j*16 + kgr*4 + r > qw + r16)) v += -1e9f;
          s[j][r] = v;
          mx = fmaxf(mx, v);
        }
      mx = fmaxf(mx, __shfl_xor(mx, 16));
      mx = fmaxf(mx, __shfl_xor(mx, 32));
      const float mn = fmaxf(m_r, mx);
      const float al = __expf(m_r - mn);
      m_r = mn;
      float rs = 0.f;
#pragma unroll
      for (int j = 0; j < 4; ++j){
        u16x4 pw;
#pragma unroll
        for (int r = 0; r < 4; ++r){
          const float p = __expf(s[j][r] - mn);
          rs += p;
          pw[r] = f2bf(p);
        }
        *(u16x4*)&Plds[wave][(r16*64 + j*16 + kgr*4) ^ ((r16&7)<<3)] = pw;
      }
      rs += __shfl_xor(rs, 16);
      rs += __shfl_xor(rs, 32);
      l_r = l_r*al + rs;
      float alr[4];
#pragma unroll
      for (int r = 0; r < 4; ++r)
        alr[r] = __shfl(al, (lane & 48) | (kgr*4 + r));
#pragma unroll
      for (int c = 0; c < 4; ++c)
#pragma unroll
        for (int r = 0; r < 4; ++r) O[c][r] *= alr[r];
      __syncthreads();
      __builtin_amdgcn_s_setprio(1);
#pragma unroll
      for (int kbl = 0; kbl < 2; ++kbl){
        const bf16x8 pa = *(const bf16x8*)&Plds[wave][(r16*64 + kbl*32 + kgr*8) ^ ((r16&7)<<3)];
#pragma unroll
        for (int c = 0; c < 4; ++c){
          const int hd = c*16 + r16;
          const bf16x8 vb = *(const bf16x8*)&vt[(hd*64 + kbl*32 + kgr*8) ^ (((hd>>3)&7)<<3)];
          O[c] = MFMA16(pa, vb, O[c]);
        }
      }
      __builtin_amdgcn_s_setprio(0);
    }
    u16* cp = ctx + (size_t)b*TS*TD + h*THD;
#pragma unroll
    for (int r = 0; r < 4; ++r){
      const float lr = __shfl(l_r, (lane & 48) | (kgr*4 + r));
      const float inv = 1.f / lr;
      const int qrow = qw + kgr*4 + r;
#pragma unroll
      for (int c = 0; c < 4; ++c)
        cp[(size_t)qrow*TD + c*16 + r16] = f2bf(O[c][r] * inv);
    }
  }
}

// ---------------------------------------------------------------- combine
__global__ __launch_bounds__(256)
void combine_kernel(float* __restrict__ out, const u16* __restrict__ slot_bf,
                    const int* __restrict__ token_slot){
  const int i = blockIdx.x*256 + threadIdx.x;   // over TT*TD/4
  const int t = i >> 8, c = i & 255;
  const int s0 = token_slot[t*2], s1 = token_slot[t*2+1];
  const float4 a = ((const float4*)out)[i];
  const u16x4 u = *(const u16x4*)&slot_bf[(size_t)s0*TD + c*4];
  const u16x4 w = *(const u16x4*)&slot_bf[(size_t)s1*TD + c*4];
  float4 o = { a.x + bf2f(u[0]) + bf2f(w[0]),
               a.y + bf2f(u[1]) + bf2f(w[1]),
               a.z + bf2f(u[2]) + bf2f(w[2]),
               a.w + bf2f(u[3]) + bf2f(w[3]) };
  ((float4*)out)[i] = o;
}

// ---------------------------------------------------------------- launcher
extern "C" void kernel_launch(void* const* d_in, const int* in_sizes, int n_in,
                              void* d_out, int out_size, void* d_ws, size_t ws_size,
                              hipStream_t stream){
  const float* x     = (const float*)d_in[0];
  const float* ln1_g = (const float*)d_in[2];
  const float* ln1_b = (const float*)d_in[3];
  const float* w_qkv = (const float*)d_in[4];
  const float* b_qkv = (const float*)d_in[5];
  const float* w_o   = (const float*)d_in[6];
  const float* b_o   = (const float*)d_in[7];
  const float* ln2_g = (const float*)d_in[8];
  const float* ln2_b = (const float*)d_in[9];
  const float* rw    = (const float*)d_in[10];
  const float* rb    = (const float*)d_in[11];
  const float* w1    = (const float*)d_in[12];
  const float* b1    = (const float*)d_in[13];
  const float* w2    = (const float*)d_in[14];
  const float* b2    = (const float*)d_in[15];
  float* out = (float*)d_out;

  char* wsp = (char*)d_ws;
  size_t off = 0;
  auto alloc = [&](size_t bytes)->void*{
    void* p = wsp + off; off += (bytes + 255) & ~(size_t)255; return p;
  };
  u8*  wqkv8   = (u8*) alloc((size_t)3*TD*TD);        // 3 MB [N][K] fp8
  u16* wo_bf   = (u16*)alloc((size_t)TD*TD*2);        // 2 MB
  u8*  w1t8    = (u8*) alloc((size_t)TE*TD*TF);       // 32 MB [E][F][D] fp8; reused as slot_bf
  u8*  w2t8    = (u8*) alloc((size_t)TE*TD*TF);       // 32 MB [E][D][F] fp8
  u8*  h2f8    = (u8*) alloc((size_t)TT*TD);          // 4 MB
  u8*  hidden8 = (u8*) alloc((size_t)NSLOT*TF);       // 32 MB
  char* ph1    = (char*)alloc((size_t)40*1024*1024);  // phase-1 arena
  u8*  h8      = (u8*)ph1;                            // 4 MB fp8 LN1 out
  u16* qkvbf   = (u16*)(ph1 + (size_t)TT*TD);
  u16* ctxbf   = (u16*)(ph1 + (size_t)TT*TD + (size_t)TT*3*TD*2);
  u16* slot_bf = (u16*)w1t8;                          // 16 MB (w1t8 dead after MoE1)
  int*   topidx     = (int*)alloc(TT*2*4);
  float* topw       = (float*)alloc(TT*2*4);
  int*   counts     = (int*)alloc(64);
  int*   offs       = (int*)alloc(64);
  int*   cursors    = (int*)alloc(64);
  int*   tilemap    = (int*)alloc(96*4);
  int*   assign_tok = (int*)alloc(NSLOT*4);
  float* assign_w_  = (float*)alloc(NSLOT*4);
  int*   token_slot = (int*)alloc(NSLOT*4);
  (void)ws_size; (void)in_sizes; (void)n_in; (void)out_size;

  const dim3 b256(256);
  zero_counts_kernel<<<dim3(1), dim3(64), 0, stream>>>(counts);
  cast_f8_kernel<<<dim3(3*TD*TD/4/256), b256, 0, stream>>>(w_qkv, wqkv8, 3*TD*TD/4);
  cast_bf_kernel<<<dim3(TD*TD/4/256), b256, 0, stream>>>(w_o, wo_bf, TD*TD/4);
  transpose_cast_f8_kernel<<<dim3(TF/32, TD/32, TE), b256, 0, stream>>>(w1, w1t8, TD, TF);
  transpose_cast_f8_kernel<<<dim3(TD/32, TF/32, TE), b256, 0, stream>>>(w2, w2t8, TF, TD);
  ln1_kernel<<<dim3(TT), b256, 0, stream>>>(x, ln1_g, ln1_b, h8);
  gemm_f8<0><<<dim3(QLD/128, TT/128), b256, 0, stream>>>(
      h8, wqkv8, b_qkv, nullptr, qkvbf, TD, QLD,
      nullptr, nullptr, nullptr, nullptr, nullptr);
  attn_kernel<<<dim3(TB*TH*16), b256, 0, stream>>>(qkvbf, ctxbf);
  gemm_bt<<<dim3(TD/128, TT/128), b256, 0, stream>>>(
      ctxbf, wo_bf, b_o, x, out, TD);
  ln2_router_kernel<<<dim3(TT), b256, 0, stream>>>(
      out, ln2_g, ln2_b, h2f8, rw, rb, counts, topidx, topw);
  offsets_kernel<<<dim3(1), dim3(64), 0, stream>>>(counts, offs, cursors,
      out + (size_t)TT*TD, tilemap);
  scatter_kernel<<<dim3(TT/256), b256, 0, stream>>>(
      topidx, topw, cursors, assign_tok, assign_w_, token_slot);
  gemm_f8<2><<<dim3(TF/128, MAXT128), b256, 0, stream>>>(
      h2f8, w1t8, b1, hidden8, nullptr, TD, TF,
      counts, offs, assign_tok, assign_w_, tilemap);
  gemm_f8<3><<<dim3(TD/128, MAXT128), b256, 0, stream>>>(
      hidden8, w2t8, b2, nullptr, slot_bf, TF, TD,
      counts, offs, assign_tok, assign_w_, tilemap);
  combine_kernel<<<dim3(TT*TD/4/256), b256, 0, stream>>>(out, slot_bf, token_slot);
}

// Round 14
// 586.516 us; speedup vs baseline: 1.0388x; 1.0388x over previous
//
#include <hip/hip_runtime.h>
#include <hip/hip_bf16.h>
#include <hip/hip_fp8.h>

// Problem constants
#define TB 2
#define TS 2048
#define TD 1024
#define TH 16
#define THD 64
#define TE 8
#define TKK 2
#define TF 4096
#define TT (TB*TS)      // 4096 tokens
#define QLD (3*TD)      // 3072
#define NSLOT (TT*TKK)  // 8192
#define MAXT128 72      // max live 128-row tiles over all experts

typedef unsigned short u16;
typedef unsigned char u8;
typedef __attribute__((ext_vector_type(8))) __bf16 bf16x8;
typedef __attribute__((ext_vector_type(8))) u16 u16x8;
typedef __attribute__((ext_vector_type(4))) u16 u16x4;
typedef __attribute__((ext_vector_type(4))) u8 u8x4;
typedef __attribute__((ext_vector_type(8))) u8 u8x8;
typedef __attribute__((ext_vector_type(4))) float f32x4;

static __device__ __forceinline__ u16 f2bf(float f){
  __hip_bfloat16 h = __float2bfloat16(f);
  return __builtin_bit_cast(u16, h);
}
static __device__ __forceinline__ float bf2f(u16 b){
  return __builtin_bit_cast(float, (unsigned)b << 16);
}
static __device__ __forceinline__ u8 f2e4m3(float f){
  __hip_fp8_e4m3 q(f);           // OCP e4m3fn on gfx950
  return q.__x;
}

#define MFMA16(a,b,c) __builtin_amdgcn_mfma_f32_16x16x32_bf16((a),(b),(c),0,0,0)
#define MFMA8(a,b,c)  __builtin_amdgcn_mfma_f32_16x16x32_fp8_fp8((a),(b),(c),0,0,0)
#define GLL16(g, l) __builtin_amdgcn_global_load_lds( \
    (const __attribute__((address_space(1))) unsigned int*)(g), \
    (__attribute__((address_space(3))) unsigned int*)(l), 16, 0, 0)

// ---------------------------------------------------------------- utilities
__global__ __launch_bounds__(256)
void cast_bf_kernel(const float* __restrict__ in, u16* __restrict__ out, int n4){
  int i = blockIdx.x*256 + threadIdx.x;
  if (i < n4){
    float4 v = ((const float4*)in)[i];
    u16x4 o = { f2bf(v.x), f2bf(v.y), f2bf(v.z), f2bf(v.w) };
    ((u16x4*)out)[i] = o;
  }
}

__global__ __launch_bounds__(256)
void cast_f8_kernel(const float* __restrict__ in, u8* __restrict__ out, int n4){
  int i = blockIdx.x*256 + threadIdx.x;
  if (i < n4){
    float4 v = ((const float4*)in)[i];
    u8x4 o = { f2e4m3(v.x), f2e4m3(v.y), f2e4m3(v.z), f2e4m3(v.w) };
    ((u8x4*)out)[i] = o;
  }
}

// out[z][c][r] = (fp8) in[z][r][c]   (R mult of 64, C mult of 32)
// 64x32 tile; u8x8 stores: 64 B contiguous per 8 lanes (vs 1 B/lane before).
__global__ __launch_bounds__(256)
void transpose_cast_f8_kernel(const float* __restrict__ in, u8* __restrict__ out,
                              int R, int C){
  __shared__ float tile[64][33];
  const size_t mo = (size_t)blockIdx.z * R * C;
  const float* ip = in + mo;
  u8* op = out + mo;
  const int c0 = blockIdx.x*32, r0 = blockIdx.y*64;
  const int lx = threadIdx.x & 31, ly = threadIdx.x >> 5;   // 32 x 8
#pragma unroll
  for (int i2 = 0; i2 < 8; ++i2)
    tile[ly + i2*8][lx] = ip[(size_t)(r0 + ly + i2*8)*C + c0 + lx];
  __syncthreads();
  const int cc = threadIdx.x >> 3, rq = (threadIdx.x & 7)*8;
  u8x8 o;
#pragma unroll
  for (int q = 0; q < 8; ++q) o[q] = f2e4m3(tile[rq + q][cc]);
  *(u8x8*)&op[(size_t)(c0 + cc)*R + r0 + rq] = o;
}

__global__ void zero_counts_kernel(int* counts){
  if (threadIdx.x < TE) counts[threadIdx.x] = 0;
}

// ---------------------------------------- layernorm 1 (fp8 out for QKV GEMM)
__global__ __launch_bounds__(256)
void ln1_kernel(const float* __restrict__ x, const float* __restrict__ g,
                const float* __restrict__ bb, u8* __restrict__ h8){
  const int t = blockIdx.x, tid = threadIdx.x;
  const float4 v = ((const float4*)(x + (size_t)t*TD))[tid];
  float s  = v.x + v.y + v.z + v.w;
  float ss = v.x*v.x + v.y*v.y + v.z*v.z + v.w*v.w;
#pragma unroll
  for (int d = 32; d >= 1; d >>= 1){ s += __shfl_down(s, d); ss += __shfl_down(ss, d); }
  __shared__ float red[8];
  const int lane = tid & 63, wave = tid >> 6;
  if (lane == 0){ red[wave] = s; red[4+wave] = ss; }
  __syncthreads();
  const float S  = red[0]+red[1]+red[2]+red[3];
  const float SS = red[4]+red[5]+red[6]+red[7];
  const float mu = S * (1.f/TD);
  const float rstd = rsqrtf(SS*(1.f/TD) - mu*mu + 1e-5f);
  const float4 gv = ((const float4*)g)[tid];
  const float4 bv = ((const float4*)bb)[tid];
  u8x4 o = { f2e4m3((v.x-mu)*rstd*gv.x + bv.x),
             f2e4m3((v.y-mu)*rstd*gv.y + bv.y),
             f2e4m3((v.z-mu)*rstd*gv.z + bv.z),
             f2e4m3((v.w-mu)*rstd*gv.w + bv.w) };
  ((u8x4*)(h8 + (size_t)t*TD))[tid] = o;
}

// --------------------- layernorm 2 + fp32 router (h2 emitted as fp8 for MoE)
__global__ __launch_bounds__(256)
void ln2_router_kernel(const float* __restrict__ xo, const float* __restrict__ g,
                       const float* __restrict__ bb, u8* __restrict__ h2f8,
                       const float* __restrict__ rw, const float* __restrict__ rb,
                       int* __restrict__ counts, int* __restrict__ topidx,
                       float* __restrict__ topw){
  const int t = blockIdx.x, tid = threadIdx.x;
  const float4 v = ((const float4*)(xo + (size_t)t*TD))[tid];
  float s  = v.x + v.y + v.z + v.w;
  float ss = v.x*v.x + v.y*v.y + v.z*v.z + v.w*v.w;
#pragma unroll
  for (int d = 32; d >= 1; d >>= 1){ s += __shfl_down(s, d); ss += __shfl_down(ss, d); }
  __shared__ float red[8];
  const int lane = tid & 63, wave = tid >> 6;
  if (lane == 0){ red[wave] = s; red[4+wave] = ss; }
  __syncthreads();
  const float S  = red[0]+red[1]+red[2]+red[3];
  const float SS = red[4]+red[5]+red[6]+red[7];
  const float mu = S * (1.f/TD);
  const float rstd = rsqrtf(SS*(1.f/TD) - mu*mu + 1e-5f);
  const float4 gv = ((const float4*)g)[tid];
  const float4 bv = ((const float4*)bb)[tid];
  float hv[4] = { (v.x-mu)*rstd*gv.x + bv.x, (v.y-mu)*rstd*gv.y + bv.y,
                  (v.z-mu)*rstd*gv.z + bv.z, (v.w-mu)*rstd*gv.w + bv.w };
  u8x4 o8 = { f2e4m3(hv[0]), f2e4m3(hv[1]), f2e4m3(hv[2]), f2e4m3(hv[3]) };
  ((u8x4*)(h2f8 + (size_t)t*TD))[tid] = o8;

  float acc[TE] = {0,0,0,0,0,0,0,0};
#pragma unroll
  for (int q = 0; q < 4; ++q){
    const int d = tid*4 + q;
    const float4 r0 = ((const float4*)(rw + (size_t)d*TE))[0];
    const float4 r1 = ((const float4*)(rw + (size_t)d*TE))[1];
    acc[0] += hv[q]*r0.x; acc[1] += hv[q]*r0.y; acc[2] += hv[q]*r0.z; acc[3] += hv[q]*r0.w;
    acc[4] += hv[q]*r1.x; acc[5] += hv[q]*r1.y; acc[6] += hv[q]*r1.z; acc[7] += hv[q]*r1.w;
  }
#pragma unroll
  for (int d = 32; d >= 1; d >>= 1)
#pragma unroll
    for (int e = 0; e < TE; ++e) acc[e] += __shfl_down(acc[e], d);
  __shared__ float racc[4][TE];
  if (lane == 0)
#pragma unroll
    for (int e = 0; e < TE; ++e) racc[wave][e] = acc[e];
  __syncthreads();
  if (tid == 0){
    float lg[TE];
#pragma unroll
    for (int e = 0; e < TE; ++e)
      lg[e] = racc[0][e] + racc[1][e] + racc[2][e] + racc[3][e] + rb[e];
    int e1 = 0;
    for (int e = 1; e < TE; ++e) if (lg[e] > lg[e1]) e1 = e;
    int e2 = -1;
    for (int e = 0; e < TE; ++e){ if (e == e1) continue; if (e2 < 0 || lg[e] > lg[e2]) e2 = e; }
    const float w1 = 1.f / (1.f + __expf(lg[e2] - lg[e1]));
    const float w2 = 1.f / (1.f + __expf(lg[e1] - lg[e2]));
    topidx[t*2]   = e1;  topidx[t*2+1] = e2;
    topw[t*2]     = w1;  topw[t*2+1]   = w2;
    atomicAdd(&counts[e1], 1);
    atomicAdd(&counts[e2], 1);
  }
}

// offsets + compact 128-row tile map (tilemap[i] = (e<<16)|mt ; tilemap[95] = nt)
__global__ void offsets_kernel(const int* __restrict__ counts, int* __restrict__ offs,
                               int* __restrict__ cursors, float* __restrict__ load_out,
                               int* __restrict__ tilemap){
  if (threadIdx.x == 0){
    int off = 0, nt = 0;
    for (int e = 0; e < TE; ++e){
      offs[e] = off; cursors[e] = off;
      load_out[e] = (float)counts[e];
      for (int mt = 0; mt*128 < counts[e]; ++mt) tilemap[nt++] = (e << 16) | mt;
      off += counts[e];
    }
    tilemap[95] = nt;
  }
}

__global__ __launch_bounds__(256)
void scatter_kernel(const int* __restrict__ topidx, const float* __restrict__ topw,
                    int* __restrict__ cursors, int* __restrict__ assign_tok,
                    float* __restrict__ assign_w, int* __restrict__ token_slot){
  const int t = blockIdx.x*256 + threadIdx.x;
  if (t >= TT) return;
#pragma unroll
  for (int k = 0; k < 2; ++k){
    const int e = topidx[t*2 + k];
    const int pos = atomicAdd(&cursors[e], 1);
    assign_tok[pos] = t;
    assign_w[pos]   = topw[t*2 + k];
    token_slot[t*2 + k] = pos;
  }
}

// ------------------- 128x128 bf16 GEMM (m97 structure) — O-proj only
__global__ __launch_bounds__(256)
void gemm_bt(const u16* __restrict__ A, const u16* __restrict__ Bt,
             const float* __restrict__ bias, const float* __restrict__ resid,
             float* __restrict__ outF, const int K)
{
  __shared__ u16 As[2][128*32];
  __shared__ u16 Bs[2][128*32];
  const int tid = threadIdx.x;
  const int n0  = blockIdx.x * 128;
  const int row0 = blockIdx.y * 128;
  const int srow = tid >> 2, skseg = tid & 3;
  const u16* aptr[2];
  const u16* bptr[2];
#pragma unroll
  for (int it = 0; it < 2; ++it){
    const int r = it*64 + srow;
    aptr[it] = A + (size_t)(row0 + r)*K + skseg*8;
    bptr[it] = Bt + (size_t)(n0 + it*64 + srow)*K + skseg*8;
  }

#define STAGE(buf, kt) do {                                        \
    _Pragma("unroll")                                              \
    for (int it = 0; it < 2; ++it){                                \
      GLL16(aptr[it] + (size_t)(kt)*32, &As[buf][it*2048 + tid*8]);\
      GLL16(bptr[it] + (size_t)(kt)*32, &Bs[buf][it*2048 + tid*8]);\
    } } while(0)

  const int lane = tid & 63, wave = tid >> 6;
  const int wm = (wave >> 1) * 64, wn = (wave & 1) * 64;
  const int r16 = lane & 15, kgr = lane >> 4;
  const f32x4 z4 = {0.f,0.f,0.f,0.f};
  f32x4 acc[4][4];
#pragma unroll
  for (int i = 0; i < 4; ++i)
#pragma unroll
    for (int j = 0; j < 4; ++j) acc[i][j] = z4;

  STAGE(0, 0);
  __syncthreads();
  const int nk = K >> 5;
  for (int kt = 0; kt < nk; ++kt){
    const int cur = kt & 1;
    if (kt + 1 < nk) STAGE(cur ^ 1, kt + 1);
    bf16x8 a[4], b[4];
#pragma unroll
    for (int i = 0; i < 4; ++i)
      a[i] = *(const bf16x8*)&As[cur][(wm + i*16 + r16)*32 + kgr*8];
#pragma unroll
    for (int j = 0; j < 4; ++j)
      b[j] = *(const bf16x8*)&Bs[cur][(wn + j*16 + r16)*32 + kgr*8];
#pragma unroll
    for (int i = 0; i < 4; ++i)
#pragma unroll
      for (int j = 0; j < 4; ++j)
        acc[i][j] = MFMA16(a[i], b[j], acc[i][j]);
    __syncthreads();
  }
#undef STAGE

#pragma unroll
  for (int i = 0; i < 4; ++i){
#pragma unroll
    for (int r = 0; r < 4; ++r){
      const int row = wm + i*16 + kgr*4 + r;
#pragma unroll
      for (int j = 0; j < 4; ++j){
        const int col = n0 + wn + j*16 + r16;
        const size_t idx = (size_t)(row0 + row)*TD + col;
        outF[idx] = acc[i][j][r] + bias[col] + resid[idx];
      }
    }
  }
}

// ------------------- 128x128 fp8 GEMM — QKV + MoE (round-12 version, verbatim:
// best measured 113 µs/MoE, FETCH 47.8 MB; residual 8.9e6 bank conflicts are
// ~5% of block time — measured negligible, do not chase).
// MODE 0: QKV  outBf = acc + bias (dense rows, QLD stride)
// MODE 2: MOE1 out8  = fp8(gelu(acc + b1[e]))  (A rows via assign_tok)
// MODE 3: MOE2 outBf = bf16((acc + b2[e]) * w[slot]) (TD stride)
template<int MODE>
__global__ __launch_bounds__(256)
void gemm_f8(const u8* __restrict__ A, const u8* __restrict__ Bt,
             const float* __restrict__ bias,
             u8* __restrict__ out8, u16* __restrict__ outBf,
             const int K, const int N,
             const int* __restrict__ counts, const int* __restrict__ offs,
             const int* __restrict__ assign_tok, const float* __restrict__ assign_w,
             const int* __restrict__ tilemap)
{
  __shared__ u8 As[2][128*32];
  __shared__ u8 Bs[2][128*32];
  const int tid = threadIdx.x;
  const int n0 = blockIdx.x * 128;
  int row0 = 0, slotbase = 0, cntRem = 128, slotEnd = 0;
  if (MODE == 0){
    row0 = blockIdx.y * 128;
  } else {
    const int nt = tilemap[95];
    if ((int)blockIdx.y >= nt) return;
    const int ent = tilemap[blockIdx.y];
    const int e = ent >> 16, mt = ent & 0xffff;
    const int cnt = counts[e];
    slotbase = offs[e] + mt*128;
    slotEnd  = offs[e] + cnt;
    cntRem   = cnt - mt*128; if (cntRem > 128) cntRem = 128;
    Bt   += (size_t)e*K*N;
    bias += (size_t)e*N;
  }

  // staging: thread t -> LDS row t>>1, 16B half t&1 (dest linear tid*16);
  // source column pre-swizzled by the same 16B involution the reader uses.
  const int srow = tid >> 1, sseg = tid & 1;
  const int scol = (sseg ^ ((srow >> 2) & 1)) * 16;
  const u8* aptr;
  const u8* bptr;
  if (MODE == 0){
    aptr = A + (size_t)(row0 + srow)*K + scol;
  } else {
    int s2 = slotbase + srow; if (s2 > slotEnd-1) s2 = slotEnd-1;
    if (MODE == 2) aptr = A + (size_t)assign_tok[s2]*K + scol;
    else           aptr = A + (size_t)s2*K + scol;
  }
  bptr = Bt + (size_t)(n0 + srow)*K + scol;
#define STAGE8(buf, kt) do{ \
    GLL16(aptr + (size_t)(kt)*32, &As[buf][tid*16]); \
    GLL16(bptr + (size_t)(kt)*32, &Bs[buf][tid*16]); }while(0)

  const int lane = tid & 63, wave = tid >> 6;
  const int wm = (wave >> 1) * 64, wn = (wave & 1) * 64;
  const int r16 = lane & 15, kgr = lane >> 4;
  // swizzled fragment offsets (per 16-row block of the 64-row wave tile)
  int offA[4], offB[4];
#pragma unroll
  for (int f = 0; f < 4; ++f){
    const int ra = wm + f*16 + r16;
    offA[f] = ra*32 + ((kgr*8) ^ (((ra >> 2) & 1) << 4));
    const int rb = wn + f*16 + r16;
    offB[f] = rb*32 + ((kgr*8) ^ (((rb >> 2) & 1) << 4));
  }
  const f32x4 z4 = {0.f,0.f,0.f,0.f};
  f32x4 acc[4][4];
#pragma unroll
  for (int i = 0; i < 4; ++i)
#pragma unroll
    for (int j = 0; j < 4; ++j) acc[i][j] = z4;

  STAGE8(0, 0);
  __syncthreads();
  const int nk = K >> 5;          // 32 fp8 elements per K-step
  for (int kt = 0; kt < nk; ++kt){
    const int cur = kt & 1;
    if (kt + 1 < nk) STAGE8(cur ^ 1, kt + 1);
    long a[4], b[4];
#pragma unroll
    for (int i = 0; i < 4; ++i) a[i] = *(const long*)&As[cur][offA[i]];
#pragma unroll
    for (int j = 0; j < 4; ++j) b[j] = *(const long*)&Bs[cur][offB[j]];
#pragma unroll
    for (int i = 0; i < 4; ++i)
#pragma unroll
      for (int j = 0; j < 4; ++j)
        acc[i][j] = MFMA8(a[i], b[j], acc[i][j]);
    __syncthreads();
  }
#undef STAGE8

#pragma unroll
  for (int i = 0; i < 4; ++i){
#pragma unroll
    for (int r = 0; r < 4; ++r){
      const int row = wm + i*16 + kgr*4 + r;
      if (MODE != 0 && row >= cntRem) continue;
#pragma unroll
      for (int j = 0; j < 4; ++j){
        const int col = n0 + wn + j*16 + r16;
        float v = acc[i][j][r] + bias[col];
        if (MODE == 0){
          outBf[(size_t)(row0 + row)*QLD + col] = f2bf(v);
        } else if (MODE == 2){
          // gelu_tanh(v) == v * sigmoid(2*0.7978845608*(v + 0.044715 v^3))
          const float z = 1.5957691216057308f*(v + 0.044715f*v*v*v);
          const float g = v * __builtin_amdgcn_rcpf(1.f + __expf(-z));
          out8[(size_t)(slotbase + row)*TF + col] = f2e4m3(g);
        } else {
          outBf[(size_t)(slotbase + row)*TD + col] =
              f2bf(v * assign_w[slotbase + row]);
        }
      }
    }
  }
}

// ------------------------------------------------------- flash attention
__global__ __launch_bounds__(256)
void attn_kernel(const u16* __restrict__ qkv, u16* __restrict__ ctx){
  const int blk = blockIdx.x;
  const int pq = blk & 15, bh = blk >> 4;
  const int b = bh >> 4, h = bh & 15;
  const int tid = threadIdx.x, lane = tid & 63, wave = tid >> 6;
  const int r16 = lane & 15, kgr = lane >> 4;
  const size_t base = (size_t)b * TS * QLD;
  const u16* Q  = qkv + base + h*THD;
  const u16* Kp = qkv + base + TD + h*THD;
  const u16* Vp = qkv + base + 2*TD + h*THD;

  __shared__ u16 VT[2][64*64];     // V^T [hd][kv], XOR-swizzled
  __shared__ u16 Plds[4][16*64];   // per-wave P [q][kv], XOR-swizzled

  const int kvr0 = tid >> 3,          hs0 = tid & 7;
  const int kvr1 = (tid + 256) >> 3,  hs1 = tid & 7;
  const f32x4 z4 = {0.f,0.f,0.f,0.f};

  for (int qsel = 0; qsel < 2; ++qsel){
    const int qt = qsel ? (31 - pq) : pq;
    const int qw = qt*64 + wave*16;

    const bf16x8 qa0 = *(const bf16x8*)&Q[(size_t)(qw + r16)*QLD + kgr*8];
    const bf16x8 qa1 = *(const bf16x8*)&Q[(size_t)(qw + r16)*QLD + 32 + kgr*8];

    f32x4 O[4] = { z4, z4, z4, z4 };
    float m_r = -1e30f;
    float l_r = 0.f;

    u16x8 v0 = *(const u16x8*)&Vp[(size_t)kvr0*QLD + hs0*8];
    u16x8 v1 = *(const u16x8*)&Vp[(size_t)kvr1*QLD + hs1*8];

    __syncthreads();

    for (int kt = 0; kt <= qt; ++kt){
      const int kv0 = kt*64;
      u16* vt = &VT[kt & 1][0];
#pragma unroll
      for (int jj = 0; jj < 8; ++jj)
        vt[((hs0*8 + jj)*64 + kvr0) ^ (hs0<<3)] = v0[jj];
#pragma unroll
      for (int jj = 0; jj < 8; ++jj)
        vt[((hs1*8 + jj)*64 + kvr1) ^ (hs1<<3)] = v1[jj];
      if (kt < qt){
        v0 = *(const u16x8*)&Vp[(size_t)(kv0 + 64 + kvr0)*QLD + hs0*8];
        v1 = *(const u16x8*)&Vp[(size_t)(kv0 + 64 + kvr1)*QLD + hs1*8];
      }
      f32x4 s[4];
      __builtin_amdgcn_s_setprio(1);
#pragma unroll
      for (int j = 0; j < 4; ++j){
        const bf16x8 k0 = *(const bf16x8*)&Kp[(size_t)(kv0 + j*16 + r16)*QLD + kgr*8];
        const bf16x8 k1 = *(const bf16x8*)&Kp[(size_t)(kv0 + j*16 + r16)*QLD + 32 + kgr*8];
        s[j] = MFMA16(k0, qa0, z4);
        s[j] = MFMA16(k1, qa1, s[j]);
      }
      __builtin_amdgcn_s_setprio(0);
      const bool diag = (kt == qt);
      float mx = -3e38f;
#pragma unroll
      for (int j = 0; j < 4; ++j)
#pragma unroll
        for (int r = 0; r < 4; ++r){
          float v = s[j][r] * 0.125f;
          if (diag && (kv0 + j*16 + kgr*4 + r > qw + r16)) v += -1e9f;
          s[j][r] = v;
          mx = fmaxf(mx, v);
        }
      mx = fmaxf(mx, __shfl_xor(mx, 16));
      mx = fmaxf(mx, __shfl_xor(mx, 32));
      const float mn = fmaxf(m_r, mx);
      const float al = __expf(m_r - mn);
      m_r = mn;
      float rs = 0.f;
#pragma unroll
      for (int j = 0; j < 4; ++j){
        u16x4 pw;
#pragma unroll
        for (int r = 0; r < 4; ++r){
          const float p = __expf(s[j][r] - mn);
          rs += p;
          pw[r] = f2bf(p);
        }
        *(u16x4*)&Plds[wave][(r16*64 + j*16 + kgr*4) ^ ((r16&7)<<3)] = pw;
      }
      rs += __shfl_xor(rs, 16);
      rs += __shfl_xor(rs, 32);
      l_r = l_r*al + rs;
      float alr[4];
#pragma unroll
      for (int r = 0; r < 4; ++r)
        alr[r] = __shfl(al, (lane & 48) | (kgr*4 + r));
#pragma unroll
      for (int c = 0; c < 4; ++c)
#pragma unroll
        for (int r = 0; r < 4; ++r) O[c][r] *= alr[r];
      __syncthreads();
      __builtin_amdgcn_s_setprio(1);
#pragma unroll
      for (int kbl = 0; kbl < 2; ++kbl){
        const bf16x8 pa = *(const bf16x8*)&Plds[wave][(r16*64 + kbl*32 + kgr*8) ^ ((r16&7)<<3)];
#pragma unroll
        for (int c = 0; c < 4; ++c){
          const int hd = c*16 + r16;
          const bf16x8 vb = *(const bf16x8*)&vt[(hd*64 + kbl*32 + kgr*8) ^ (((hd>>3)&7)<<3)];
          O[c] = MFMA16(pa, vb, O[c]);
        }
      }
      __builtin_amdgcn_s_setprio(0);
    }
    u16* cp = ctx + (size_t)b*TS*TD + h*THD;
#pragma unroll
    for (int r = 0; r < 4; ++r){
      const float lr = __shfl(l_r, (lane & 48) | (kgr*4 + r));
      const float inv = 1.f / lr;
      const int qrow = qw + kgr*4 + r;
#pragma unroll
      for (int c = 0; c < 4; ++c)
        cp[(size_t)qrow*TD + c*16 + r16] = f2bf(O[c][r] * inv);
    }
  }
}

// ---------------------------------------------------------------- combine
__global__ __launch_bounds__(256)
void combine_kernel(float* __restrict__ out, const u16* __restrict__ slot_bf,
                    const int* __restrict__ token_slot){
  const int i = blockIdx.x*256 + threadIdx.x;   // over TT*TD/4
  const int t = i >> 8, c = i & 255;
  const int s0 = token_slot[t*2], s1 = token_slot[t*2+1];
  const float4 a = ((const float4*)out)[i];
  const u16x4 u = *(const u16x4*)&slot_bf[(size_t)s0*TD + c*4];
  const u16x4 w = *(const u16x4*)&slot_bf[(size_t)s1*TD + c*4];
  float4 o = { a.x + bf2f(u[0]) + bf2f(w[0]),
               a.y + bf2f(u[1]) + bf2f(w[1]),
               a.z + bf2f(u[2]) + bf2f(w[2]),
               a.w + bf2f(u[3]) + bf2f(w[3]) };
  ((float4*)out)[i] = o;
}

// ---------------------------------------------------------------- launcher
extern "C" void kernel_launch(void* const* d_in, const int* in_sizes, int n_in,
                              void* d_out, int out_size, void* d_ws, size_t ws_size,
                              hipStream_t stream){
  const float* x     = (const float*)d_in[0];
  const float* ln1_g = (const float*)d_in[2];
  const float* ln1_b = (const float*)d_in[3];
  const float* w_qkv = (const float*)d_in[4];
  const float* b_qkv = (const float*)d_in[5];
  const float* w_o   = (const float*)d_in[6];
  const float* b_o   = (const float*)d_in[7];
  const float* ln2_g = (const float*)d_in[8];
  const float* ln2_b = (const float*)d_in[9];
  const float* rw    = (const float*)d_in[10];
  const float* rb    = (const float*)d_in[11];
  const float* w1    = (const float*)d_in[12];
  const float* b1    = (const float*)d_in[13];
  const float* w2    = (const float*)d_in[14];
  const float* b2    = (const float*)d_in[15];
  float* out = (float*)d_out;

  char* wsp = (char*)d_ws;
  size_t off = 0;
  auto alloc = [&](size_t bytes)->void*{
    void* p = wsp + off; off += (bytes + 255) & ~(size_t)255; return p;
  };
  u8*  wqkv8   = (u8*) alloc((size_t)3*TD*TD);        // 3 MB [N][K] fp8
  u16* wo_bf   = (u16*)alloc((size_t)TD*TD*2);        // 2 MB
  u8*  w1t8    = (u8*) alloc((size_t)TE*TD*TF);       // 32 MB [E][F][D] fp8; reused as slot_bf
  u8*  w2t8    = (u8*) alloc((size_t)TE*TD*TF);       // 32 MB [E][D][F] fp8
  u8*  h2f8    = (u8*) alloc((size_t)TT*TD);          // 4 MB
  u8*  hidden8 = (u8*) alloc((size_t)NSLOT*TF);       // 32 MB
  char* ph1    = (char*)alloc((size_t)40*1024*1024);  // phase-1 arena
  u8*  h8      = (u8*)ph1;                            // 4 MB fp8 LN1 out
  u16* qkvbf   = (u16*)(ph1 + (size_t)TT*TD);
  u16* ctxbf   = (u16*)(ph1 + (size_t)TT*TD + (size_t)TT*3*TD*2);
  u16* slot_bf = (u16*)w1t8;                          // 16 MB (w1t8 dead after MoE1)
  int*   topidx     = (int*)alloc(TT*2*4);
  float* topw       = (float*)alloc(TT*2*4);
  int*   counts     = (int*)alloc(64);
  int*   offs       = (int*)alloc(64);
  int*   cursors    = (int*)alloc(64);
  int*   tilemap    = (int*)alloc(96*4);
  int*   assign_tok = (int*)alloc(NSLOT*4);
  float* assign_w_  = (float*)alloc(NSLOT*4);
  int*   token_slot = (int*)alloc(NSLOT*4);
  (void)ws_size; (void)in_sizes; (void)n_in; (void)out_size;

  const dim3 b256(256);
  zero_counts_kernel<<<dim3(1), dim3(64), 0, stream>>>(counts);
  cast_f8_kernel<<<dim3(3*TD*TD/4/256), b256, 0, stream>>>(w_qkv, wqkv8, 3*TD*TD/4);
  cast_bf_kernel<<<dim3(TD*TD/4/256), b256, 0, stream>>>(w_o, wo_bf, TD*TD/4);
  transpose_cast_f8_kernel<<<dim3(TF/32, TD/64, TE), b256, 0, stream>>>(w1, w1t8, TD, TF);
  transpose_cast_f8_kernel<<<dim3(TD/32, TF/64, TE), b256, 0, stream>>>(w2, w2t8, TF, TD);
  ln1_kernel<<<dim3(TT), b256, 0, stream>>>(x, ln1_g, ln1_b, h8);
  gemm_f8<0><<<dim3(QLD/128, TT/128), b256, 0, stream>>>(
      h8, wqkv8, b_qkv, nullptr, qkvbf, TD, QLD,
      nullptr, nullptr, nullptr, nullptr, nullptr);
  attn_kernel<<<dim3(TB*TH*16), b256, 0, stream>>>(qkvbf, ctxbf);
  gemm_bt<<<dim3(TD/128, TT/128), b256, 0, stream>>>(
      ctxbf, wo_bf, b_o, x, out, TD);
  ln2_router_kernel<<<dim3(TT), b256, 0, stream>>>(
      out, ln2_g, ln2_b, h2f8, rw, rb, counts, topidx, topw);
  offsets_kernel<<<dim3(1), dim3(64), 0, stream>>>(counts, offs, cursors,
      out + (size_t)TT*TD, tilemap);
  scatter_kernel<<<dim3(TT/256), b256, 0, stream>>>(
      topidx, topw, cursors, assign_tok, assign_w_, token_slot);
  gemm_f8<2><<<dim3(TF/128, MAXT128), b256, 0, stream>>>(
      h2f8, w1t8, b1, hidden8, nullptr, TD, TF,
      counts, offs, assign_tok, assign_w_, tilemap);
  gemm_f8<3><<<dim3(TD/128, MAXT128), b256, 0, stream>>>(
      hidden8, w2t8, b2, nullptr, slot_bf, TF, TD,
      counts, offs, assign_tok, assign_w_, tilemap);
  combine_kernel<<<dim3(TT*TD/4/256), b256, 0, stream>>>(out, slot_bf, token_slot);
}